// Round 12
// baseline (445.318 us; speedup 1.0000x reference)
//
#include <hip/hip_runtime.h>
#include <hip/hip_bf16.h>

// Problem constants (B=64, T=512, I=256, H=512)
#define BATCH 64
#define TSTEPS 512
#define IDIM 256
#define HDIM 512
#define MROWS (BATCH * TSTEPS)   // 32768

typedef __attribute__((ext_vector_type(8))) unsigned short ushort8;

typedef __attribute__((address_space(1))) const void gvoid;
typedef __attribute__((address_space(3))) void lvoid;

__device__ __forceinline__ void gl2lds16(const void* g, void* l) {
    // async global->LDS, 16B per lane; LDS dest = wave-uniform base + lane*16
    __builtin_amdgcn_global_load_lds((gvoid*)g, (lvoid*)l, 16, 0, 0);
}

// ---------------------------------------------------------------------------
// K0: extract center taps: W1T[i][h] = conv1_w[h][i][1] ([k][n] layout);
//                          W2T[h][j] = conv2_w[j][h][1] ([k][n] layout)
// ---------------------------------------------------------------------------
__global__ void extract_weights(const float* __restrict__ c1w,
                                const float* __restrict__ c2w,
                                float* __restrict__ W1T,
                                float* __restrict__ W2T) {
    int tid = blockIdx.x * 256 + threadIdx.x;
    if (tid < IDIM * HDIM) {
        int i = tid >> 9;          // / 512
        int h = tid & 511;
        W1T[tid] = c1w[(h * IDIM + i) * 3 + 1];
    }
    if (tid < HDIM * HDIM) {
        int h = tid >> 9;
        int j = tid & 511;
        W2T[tid] = c2w[(j * HDIM + h) * 3 + 1];
    }
}

// ---------------------------------------------------------------------------
// G1 GEMM — R4 shape verbatim (fp32 A). NUMERICS CONTRACT: one sequential
// k-ascending fp32 fmaf chain per output — bitwise identical to numpy's
// k-sequential sgemm (absmax 0.0 in rounds 1/4/5/7/8/11).
// ---------------------------------------------------------------------------
#define BM 128
#define BN 128
#define BK 16

__global__ __launch_bounds__(256, 2) void gemm_f32(const float* __restrict__ A,
                                                   const float* __restrict__ BT,
                                                   const float* __restrict__ bias,
                                                   float* __restrict__ C,
                                                   int K, int addBias) {
    __shared__ __align__(16) float As[BK * BM];   // [k][m]  8 KB
    __shared__ __align__(16) float Bs[BK * BN];   // [k][n]  8 KB

    const int N = HDIM;
    int tid  = threadIdx.x;
    int lane = tid & 63;
    int wave = tid >> 6;
    int row0 = blockIdx.x * BM;
    int col0 = blockIdx.y * BN;
    int wm = (wave >> 1) * 64;
    int wn = (wave & 1) * 64;
    int mbase = wm + (lane >> 3) * 8;
    int nbase = wn + (lane & 7) * 8;

    float acc[8][8];
#pragma unroll
    for (int i = 0; i < 8; i++)
#pragma unroll
        for (int j = 0; j < 8; j++) acc[i][j] = 0.0f;

    int ar = tid >> 1;
    int ak = (tid & 1) * 8;
    const float* ap = A + (size_t)(row0 + ar) * K + ak;

    const char* bp = (const char*)(BT + (size_t)(tid >> 5) * N + col0) + (tid & 31) * 16;
    char* bld = (char*)Bs + tid * 16;
    const size_t bRow8 = (size_t)8 * N * sizeof(float);

    for (int k0 = 0; k0 < K; k0 += BK) {
        gl2lds16(bp, bld);
        gl2lds16(bp + bRow8, bld + 4096);
        float4 a0 = *(const float4*)(ap);
        float4 a1 = *(const float4*)(ap + 4);
        ap += BK;
        bp += (size_t)BK * N * sizeof(float);
        As[(ak + 0) * BM + ar] = a0.x;
        As[(ak + 1) * BM + ar] = a0.y;
        As[(ak + 2) * BM + ar] = a0.z;
        As[(ak + 3) * BM + ar] = a0.w;
        As[(ak + 4) * BM + ar] = a1.x;
        As[(ak + 5) * BM + ar] = a1.y;
        As[(ak + 6) * BM + ar] = a1.z;
        As[(ak + 7) * BM + ar] = a1.w;
        __syncthreads();

#pragma unroll
        for (int k = 0; k < BK; k++) {
            float4 av0 = *(const float4*)&As[k * BM + mbase];
            float4 av1 = *(const float4*)&As[k * BM + mbase + 4];
            float4 bv0 = *(const float4*)&Bs[k * BN + nbase];
            float4 bv1 = *(const float4*)&Bs[k * BN + nbase + 4];
            float a8[8] = {av0.x, av0.y, av0.z, av0.w, av1.x, av1.y, av1.z, av1.w};
            float b8[8] = {bv0.x, bv0.y, bv0.z, bv0.w, bv1.x, bv1.y, bv1.z, bv1.w};
#pragma unroll
            for (int i = 0; i < 8; i++)
#pragma unroll
                for (int j = 0; j < 8; j++)
                    acc[i][j] = fmaf(a8[i], b8[j], acc[i][j]);
        }
        __syncthreads();
    }

    float bb[8];
#pragma unroll
    for (int j = 0; j < 8; j++)
        bb[j] = addBias ? bias[col0 + nbase + j] : 0.0f;
#pragma unroll
    for (int i = 0; i < 8; i++) {
        int row = row0 + mbase + i;
        float4* cp = (float4*)&C[(size_t)row * N + col0 + nbase];
        cp[0] = (float4){acc[i][0] + bb[0], acc[i][1] + bb[1],
                         acc[i][2] + bb[2], acc[i][3] + bb[3]};
        cp[1] = (float4){acc[i][4] + bb[4], acc[i][5] + bb[5],
                         acc[i][6] + bb[6], acc[i][7] + bb[7]};
    }
}

// ---------------------------------------------------------------------------
// G2 GEMM — R4 skeleton with BF16-STORED A (s1 is binary; {0,1} exact in
// bf16, float(bf16) is bitwise 1.0f/0.0f -> the sequential fp32 fmaf chain
// is UNCHANGED bit-for-bit). A-fragment read: one ds_read_b128 of 8 ushorts
// per k-step (vs 2x b128 floats) -> per-wave LDS 48->36 cyc/k-step. At 10
// waves/CU: LDS ~360 vs VALU ~360-400 per k-step round -> balanced pipes
// (was 1.5x LDS-bound, VALUBusy 70%). Expansion = 1-2 shift/mask ops per
// a-value, amortized over 8 FMAs each.
// ---------------------------------------------------------------------------
__global__ __launch_bounds__(256, 2) void gemm_bf16a(
    const unsigned short* __restrict__ A,   // s1 as bf16 bits, [m][k]
    const float* __restrict__ BT,           // [k][n]
    float* __restrict__ C)                  // [m][n]
{
    __shared__ __align__(16) unsigned short AsU[BK * BM];   // [k][m]  4 KB
    __shared__ __align__(16) float Bs[BK * BN];             // [k][n]  8 KB

    const int N = HDIM;
    const int K = HDIM;
    int tid  = threadIdx.x;
    int lane = tid & 63;
    int wave = tid >> 6;
    int row0 = blockIdx.x * BM;
    int col0 = blockIdx.y * BN;
    int wm = (wave >> 1) * 64;
    int wn = (wave & 1) * 64;
    int mbase = wm + (lane >> 3) * 8;
    int nbase = wn + (lane & 7) * 8;

    float acc[8][8];
#pragma unroll
    for (int i = 0; i < 8; i++)
#pragma unroll
        for (int j = 0; j < 8; j++) acc[i][j] = 0.0f;

    // A staging: thread loads 8 consecutive ushorts (16B) of row (tid>>1),
    // k-half (tid&1)*8; scatters transposed into AsU[k][m].
    int ar = tid >> 1;
    int ak = (tid & 1) * 8;
    const unsigned short* ap = A + (size_t)(row0 + ar) * K + ak;

    const char* bp = (const char*)(BT + (size_t)(tid >> 5) * N + col0) + (tid & 31) * 16;
    char* bld = (char*)Bs + tid * 16;
    const size_t bRow8 = (size_t)8 * N * sizeof(float);

    for (int k0 = 0; k0 < K; k0 += BK) {
        gl2lds16(bp, bld);
        gl2lds16(bp + bRow8, bld + 4096);
        ushort8 au = *(const ushort8*)(ap);
        ap += BK;
        bp += (size_t)BK * N * sizeof(float);
#pragma unroll
        for (int q = 0; q < 8; q++)
            AsU[(ak + q) * BM + ar] = au[q];
        __syncthreads();

#pragma unroll
        for (int k = 0; k < BK; k++) {
            // A: 8 consecutive ushorts = one 16B read (8-way broadcast
            //    across lane-groups, conflict-free chunk spread)
            ushort8 av = *(const ushort8*)&AsU[k * BM + mbase];
            float4 bv0 = *(const float4*)&Bs[k * BN + nbase];
            float4 bv1 = *(const float4*)&Bs[k * BN + nbase + 4];
            float a8[8];
#pragma unroll
            for (int i = 0; i < 8; i++)
                a8[i] = __uint_as_float(((unsigned)av[i]) << 16);  // exact {0,1}
            float b8[8] = {bv0.x, bv0.y, bv0.z, bv0.w, bv1.x, bv1.y, bv1.z, bv1.w};
#pragma unroll
            for (int i = 0; i < 8; i++)
#pragma unroll
                for (int j = 0; j < 8; j++)
                    acc[i][j] = fmaf(a8[i], b8[j], acc[i][j]);
        }
        __syncthreads();
    }

#pragma unroll
    for (int i = 0; i < 8; i++) {
        int row = row0 + mbase + i;
        float4* cp = (float4*)&C[(size_t)row * N + col0 + nbase];
        cp[0] = (float4){acc[i][0], acc[i][1], acc[i][2], acc[i][3]};
        cp[1] = (float4){acc[i][4], acc[i][5], acc[i][6], acc[i][7]};
    }
}

// ---------------------------------------------------------------------------
// K2: per-(b,h) LIF scan, ping-pong register prefetch (R7). Writes s1 as
// bf16 {0,1} (exact). Arithmetic identical to round 1.
// ---------------------------------------------------------------------------
__global__ void lif_scan1(const float* __restrict__ z1,
                          unsigned short* __restrict__ s1,
                          const float* __restrict__ th_p) {
    int gtid = blockIdx.x * blockDim.x + threadIdx.x;   // 0..32767
    int b = gtid >> 9;
    int h = gtid & 511;
    float th = *th_p;
    const float* zp = z1 + (size_t)b * TSTEPS * HDIM + h;
    unsigned short* sp = s1 + (size_t)b * TSTEPS * HDIM + h;
    float m = 0.0f;
    float bufA[16], bufB[16];
#pragma unroll
    for (int i = 0; i < 16; i++) bufA[i] = zp[(size_t)i * HDIM];
    for (int t0 = 0; t0 < TSTEPS; t0 += 32) {
#pragma unroll
        for (int i = 0; i < 16; i++) bufB[i] = zp[(size_t)(t0 + 16 + i) * HDIM];
        {
            unsigned short ss[16];
#pragma unroll
            for (int i = 0; i < 16; i++) {
                m += bufA[i];
                float thr = m / th - 1.0f;
                ss[i] = (thr >= 0.0f) ? 0x3F80 : 0;   // bf16 1.0 / 0.0
                if (thr > 0.0f) m -= th;
            }
#pragma unroll
            for (int i = 0; i < 16; i++) sp[(size_t)(t0 + i) * HDIM] = ss[i];
        }
        if (t0 + 32 < TSTEPS) {
#pragma unroll
            for (int i = 0; i < 16; i++) bufA[i] = zp[(size_t)(t0 + 32 + i) * HDIM];
        }
        {
            unsigned short ss[16];
#pragma unroll
            for (int i = 0; i < 16; i++) {
                m += bufB[i];
                float thr = m / th - 1.0f;
                ss[i] = (thr >= 0.0f) ? 0x3F80 : 0;
                if (thr > 0.0f) m -= th;
            }
#pragma unroll
            for (int i = 0; i < 16; i++) sp[(size_t)(t0 + 16 + i) * HDIM] = ss[i];
        }
    }
}

// ---------------------------------------------------------------------------
// K4: per-(b,j) scan: m2 = (m2 + raw[t]) + bias, spike/reset -> out.
// Ping-pong prefetch (R7 version, unchanged).
// ---------------------------------------------------------------------------
__global__ void lif_scan2(const float* __restrict__ raw,
                          const float* __restrict__ b2,
                          const float* __restrict__ th_p,
                          float* __restrict__ out) {
    int gtid = blockIdx.x * blockDim.x + threadIdx.x;   // 0..32767
    int b = gtid >> 9;
    int j = gtid & 511;
    float th = *th_p;
    float bias = b2[j];
    const float* rp = raw + (size_t)b * TSTEPS * HDIM + j;
    float* op = out + (size_t)b * TSTEPS * HDIM + j;
    float m = 0.0f;
    float bufA[16], bufB[16];
#pragma unroll
    for (int i = 0; i < 16; i++) bufA[i] = rp[(size_t)i * HDIM];
    for (int t0 = 0; t0 < TSTEPS; t0 += 32) {
#pragma unroll
        for (int i = 0; i < 16; i++) bufB[i] = rp[(size_t)(t0 + 16 + i) * HDIM];
        {
            float ss[16];
#pragma unroll
            for (int i = 0; i < 16; i++) {
                m = (m + bufA[i]) + bias;
                float thr = m / th - 1.0f;
                ss[i] = (thr >= 0.0f) ? 1.0f : 0.0f;
                if (thr > 0.0f) m -= th;
            }
#pragma unroll
            for (int i = 0; i < 16; i++) op[(size_t)(t0 + i) * HDIM] = ss[i];
        }
        if (t0 + 32 < TSTEPS) {
#pragma unroll
            for (int i = 0; i < 16; i++) bufA[i] = rp[(size_t)(t0 + 32 + i) * HDIM];
        }
        {
            float ss[16];
#pragma unroll
            for (int i = 0; i < 16; i++) {
                m = (m + bufB[i]) + bias;
                float thr = m / th - 1.0f;
                ss[i] = (thr >= 0.0f) ? 1.0f : 0.0f;
                if (thr > 0.0f) m -= th;
            }
#pragma unroll
            for (int i = 0; i < 16; i++) op[(size_t)(t0 + 16 + i) * HDIM] = ss[i];
        }
    }
}

// ---------------------------------------------------------------------------
extern "C" void kernel_launch(void* const* d_in, const int* in_sizes, int n_in,
                              void* d_out, int out_size, void* d_ws, size_t ws_size,
                              hipStream_t stream) {
    const float* x    = (const float*)d_in[0];   // (64, 512, 256)
    const float* c1w  = (const float*)d_in[1];   // (512, 256, 3)
    const float* c1b  = (const float*)d_in[2];   // (512,)
    const float* c2w  = (const float*)d_in[3];   // (512, 512, 3)
    const float* c2b  = (const float*)d_in[4];   // (512,)
    const float* th1  = (const float*)d_in[5];   // scalar
    const float* th2  = (const float*)d_in[6];   // scalar
    float* out = (float*)d_out;                  // (64, 512, 512)

    // Workspace layout:
    //   W1T : 131072 f32   (512 KB)   [k=i][n=h]
    //   W2T : 262144 f32   (1 MB)     [k=h][n=j]
    //   bufA: 16777216 f32 (64 MB)    z1, later m2raw  [m][n]
    //   bufS: 16777216 u16 (32 MB)    s1 as bf16 bits  [m][h]
    float* W1T  = (float*)d_ws;
    float* W2T  = W1T + IDIM * HDIM;
    float* bufA = W2T + HDIM * HDIM;
    unsigned short* bufS = (unsigned short*)(bufA + (size_t)MROWS * HDIM);

    // K0: weight extraction
    extract_weights<<<(HDIM * HDIM + 255) / 256, 256, 0, stream>>>(c1w, c2w, W1T, W2T);

    // K1: z1 = x @ W1T + b1   (M=32768, K=256, N=512) -> bufA
    {
        dim3 grid(MROWS / BM, HDIM / BN);
        gemm_f32<<<grid, 256, 0, stream>>>(x, W1T, c1b, bufA, IDIM, 1);
    }

    // K2: s1 scan -> bufS (bf16 bits)
    lif_scan1<<<MROWS / 64, 64, 0, stream>>>(bufA, bufS, th1);

    // K3: m2raw = s1 @ W2T   (M=32768, K=512, N=512) -> bufA
    {
        dim3 grid(MROWS / BM, HDIM / BN);
        gemm_bf16a<<<grid, 256, 0, stream>>>(bufS, W2T, bufA);
    }

    // K4: s2 scan -> out
    lif_scan2<<<MROWS / 64, 64, 0, stream>>>(bufA, c2b, th2, out);
}

// Round 13
// 434.799 us; speedup vs baseline: 1.0242x; 1.0242x over previous
//
#include <hip/hip_runtime.h>

// Problem constants (B=64, T=512, I=256, H=512)
#define BATCH 64
#define TSTEPS 512
#define IDIM 256
#define HDIM 512
#define MROWS (BATCH * TSTEPS)   // 32768

typedef __attribute__((address_space(1))) const void gvoid;
typedef __attribute__((address_space(3))) void lvoid;

__device__ __forceinline__ void gl2lds16(const void* g, void* l) {
    // async global->LDS, 16B per lane; LDS dest = wave-uniform base + lane*16
    __builtin_amdgcn_global_load_lds((gvoid*)g, (lvoid*)l, 16, 0, 0);
}

// ---------------------------------------------------------------------------
// K0: extract center taps: W1T[i][h] = conv1_w[h][i][1] ([k][n] layout);
//                          W2T[h][j] = conv2_w[j][h][1] ([k][n] layout)
// ---------------------------------------------------------------------------
__global__ void extract_weights(const float* __restrict__ c1w,
                                const float* __restrict__ c2w,
                                float* __restrict__ W1T,
                                float* __restrict__ W2T) {
    int tid = blockIdx.x * 256 + threadIdx.x;
    if (tid < IDIM * HDIM) {
        int i = tid >> 9;          // / 512
        int h = tid & 511;
        W1T[tid] = c1w[(h * IDIM + i) * 3 + 1];
    }
    if (tid < HDIM * HDIM) {
        int h = tid >> 9;
        int j = tid & 511;
        W2T[tid] = c2w[(j * HDIM + h) * 3 + 1];
    }
}

// ---------------------------------------------------------------------------
// fp32 GEMM — R4 shape with BK=32 (halved barrier count).
// C[m][n] = (sum_k A[m][k]*BT[k][n]) [+ bias[n]]
// NUMERICS CONTRACT: one sequential k-ascending fp32 fmaf chain per output —
// bitwise identical to numpy's k-sequential sgemm (absmax 0.0 in rounds
// 1/4/5/7/8/11/12). MFMA / split-K / tree reductions flip spikes (R2/R3).
//
// R12 evidence: G2 is VALU-issue-bound at ~70% duty (removing LDS cycles
// didn't help; adding VALU ops cost exactly their fraction). The ~30% stall
// is the 2 barrier/staging events per 16-k-step iter. BK=32 halves events
// per k-step -> predicted stall ~15%. Staged values keep R4's short live
// ranges (loaded, scattered, THEN barrier) — avoids R10's spill cliff.
// LDS 32KB/block (<=5 blocks/CU). VGPR ~70 expected (R4 was 52).
// ---------------------------------------------------------------------------
#define BM 128
#define BN 128
#define BK 32

__global__ __launch_bounds__(256, 2) void gemm_f32(const float* __restrict__ A,
                                                   const float* __restrict__ BT,
                                                   const float* __restrict__ bias,
                                                   float* __restrict__ C,
                                                   int K, int addBias) {
    __shared__ __align__(16) float As[BK * BM];   // [k][m]  16 KB
    __shared__ __align__(16) float Bs[BK * BN];   // [k][n]  16 KB

    const int N = HDIM;
    int tid  = threadIdx.x;
    int lane = tid & 63;
    int wave = tid >> 6;
    int row0 = blockIdx.x * BM;
    int col0 = blockIdx.y * BN;
    int wm = (wave >> 1) * 64;
    int wn = (wave & 1) * 64;
    int mbase = wm + (lane >> 3) * 8;
    int nbase = wn + (lane & 7) * 8;

    float acc[8][8];
#pragma unroll
    for (int i = 0; i < 8; i++)
#pragma unroll
        for (int j = 0; j < 8; j++) acc[i][j] = 0.0f;

    // A staging: thread covers row (tid>>1), k-half (tid&1)*16: 16 floats,
    // scattered transposed into As[k][m] (2-way bank alias, free).
    int ar = tid >> 1;
    int ak = (tid & 1) * 16;
    const float* ap = A + (size_t)(row0 + ar) * K + ak;

    // B staging via gl2lds: thread covers 16B: k-row tid>>5 (0..7),
    // cols (tid&31)*4; 4 instrs at +0/+8/+16/+24 k-rows.
    const char* bp = (const char*)(BT + (size_t)(tid >> 5) * N + col0) + (tid & 31) * 16;
    char* bld = (char*)Bs + tid * 16;
    const size_t bRow8 = (size_t)8 * N * sizeof(float);

    for (int k0 = 0; k0 < K; k0 += BK) {
        gl2lds16(bp,             bld);
        gl2lds16(bp +     bRow8, bld + 4096);
        gl2lds16(bp + 2 * bRow8, bld + 8192);
        gl2lds16(bp + 3 * bRow8, bld + 12288);
        float4 a0 = *(const float4*)(ap);
        float4 a1 = *(const float4*)(ap + 4);
        float4 a2 = *(const float4*)(ap + 8);
        float4 a3 = *(const float4*)(ap + 12);
        ap += BK;
        bp += (size_t)BK * N * sizeof(float);
        As[(ak +  0) * BM + ar] = a0.x;
        As[(ak +  1) * BM + ar] = a0.y;
        As[(ak +  2) * BM + ar] = a0.z;
        As[(ak +  3) * BM + ar] = a0.w;
        As[(ak +  4) * BM + ar] = a1.x;
        As[(ak +  5) * BM + ar] = a1.y;
        As[(ak +  6) * BM + ar] = a1.z;
        As[(ak +  7) * BM + ar] = a1.w;
        As[(ak +  8) * BM + ar] = a2.x;
        As[(ak +  9) * BM + ar] = a2.y;
        As[(ak + 10) * BM + ar] = a2.z;
        As[(ak + 11) * BM + ar] = a2.w;
        As[(ak + 12) * BM + ar] = a3.x;
        As[(ak + 13) * BM + ar] = a3.y;
        As[(ak + 14) * BM + ar] = a3.z;
        As[(ak + 15) * BM + ar] = a3.w;
        __syncthreads();

#pragma unroll
        for (int k = 0; k < BK; k++) {
            float4 av0 = *(const float4*)&As[k * BM + mbase];
            float4 av1 = *(const float4*)&As[k * BM + mbase + 4];
            float4 bv0 = *(const float4*)&Bs[k * BN + nbase];
            float4 bv1 = *(const float4*)&Bs[k * BN + nbase + 4];
            float a8[8] = {av0.x, av0.y, av0.z, av0.w, av1.x, av1.y, av1.z, av1.w};
            float b8[8] = {bv0.x, bv0.y, bv0.z, bv0.w, bv1.x, bv1.y, bv1.z, bv1.w};
#pragma unroll
            for (int i = 0; i < 8; i++)
#pragma unroll
                for (int j = 0; j < 8; j++)
                    acc[i][j] = fmaf(a8[i], b8[j], acc[i][j]);
        }
        __syncthreads();
    }

    float bb[8];
#pragma unroll
    for (int j = 0; j < 8; j++)
        bb[j] = addBias ? bias[col0 + nbase + j] : 0.0f;
#pragma unroll
    for (int i = 0; i < 8; i++) {
        int row = row0 + mbase + i;
        float4* cp = (float4*)&C[(size_t)row * N + col0 + nbase];
        cp[0] = (float4){acc[i][0] + bb[0], acc[i][1] + bb[1],
                         acc[i][2] + bb[2], acc[i][3] + bb[3]};
        cp[1] = (float4){acc[i][4] + bb[4], acc[i][5] + bb[5],
                         acc[i][6] + bb[6], acc[i][7] + bb[7]};
    }
}

// ---------------------------------------------------------------------------
// K2: per-(b,h) LIF scan, ping-pong register prefetch (R7, measured win).
// Arithmetic identical to round 1 (sequential per element).
// ---------------------------------------------------------------------------
__global__ void lif_scan1(const float* __restrict__ z1,
                          float* __restrict__ s1,
                          const float* __restrict__ th_p) {
    int gtid = blockIdx.x * blockDim.x + threadIdx.x;   // 0..32767
    int b = gtid >> 9;
    int h = gtid & 511;
    float th = *th_p;
    const float* zp = z1 + (size_t)b * TSTEPS * HDIM + h;
    float* sp = s1 + (size_t)b * TSTEPS * HDIM + h;
    float m = 0.0f;
    float bufA[16], bufB[16];
#pragma unroll
    for (int i = 0; i < 16; i++) bufA[i] = zp[(size_t)i * HDIM];
    for (int t0 = 0; t0 < TSTEPS; t0 += 32) {
#pragma unroll
        for (int i = 0; i < 16; i++) bufB[i] = zp[(size_t)(t0 + 16 + i) * HDIM];
        {
            float ss[16];
#pragma unroll
            for (int i = 0; i < 16; i++) {
                m += bufA[i];
                float thr = m / th - 1.0f;
                ss[i] = (thr >= 0.0f) ? 1.0f : 0.0f;
                if (thr > 0.0f) m -= th;
            }
#pragma unroll
            for (int i = 0; i < 16; i++) sp[(size_t)(t0 + i) * HDIM] = ss[i];
        }
        if (t0 + 32 < TSTEPS) {
#pragma unroll
            for (int i = 0; i < 16; i++) bufA[i] = zp[(size_t)(t0 + 32 + i) * HDIM];
        }
        {
            float ss[16];
#pragma unroll
            for (int i = 0; i < 16; i++) {
                m += bufB[i];
                float thr = m / th - 1.0f;
                ss[i] = (thr >= 0.0f) ? 1.0f : 0.0f;
                if (thr > 0.0f) m -= th;
            }
#pragma unroll
            for (int i = 0; i < 16; i++) sp[(size_t)(t0 + 16 + i) * HDIM] = ss[i];
        }
    }
}

// ---------------------------------------------------------------------------
// K4: per-(b,j) scan: m2 = (m2 + raw[t]) + bias, spike/reset -> out.
// Ping-pong prefetch (R7 version).
// ---------------------------------------------------------------------------
__global__ void lif_scan2(const float* __restrict__ raw,
                          const float* __restrict__ b2,
                          const float* __restrict__ th_p,
                          float* __restrict__ out) {
    int gtid = blockIdx.x * blockDim.x + threadIdx.x;   // 0..32767
    int b = gtid >> 9;
    int j = gtid & 511;
    float th = *th_p;
    float bias = b2[j];
    const float* rp = raw + (size_t)b * TSTEPS * HDIM + j;
    float* op = out + (size_t)b * TSTEPS * HDIM + j;
    float m = 0.0f;
    float bufA[16], bufB[16];
#pragma unroll
    for (int i = 0; i < 16; i++) bufA[i] = rp[(size_t)i * HDIM];
    for (int t0 = 0; t0 < TSTEPS; t0 += 32) {
#pragma unroll
        for (int i = 0; i < 16; i++) bufB[i] = rp[(size_t)(t0 + 16 + i) * HDIM];
        {
            float ss[16];
#pragma unroll
            for (int i = 0; i < 16; i++) {
                m = (m + bufA[i]) + bias;
                float thr = m / th - 1.0f;
                ss[i] = (thr >= 0.0f) ? 1.0f : 0.0f;
                if (thr > 0.0f) m -= th;
            }
#pragma unroll
            for (int i = 0; i < 16; i++) op[(size_t)(t0 + i) * HDIM] = ss[i];
        }
        if (t0 + 32 < TSTEPS) {
#pragma unroll
            for (int i = 0; i < 16; i++) bufA[i] = rp[(size_t)(t0 + 32 + i) * HDIM];
        }
        {
            float ss[16];
#pragma unroll
            for (int i = 0; i < 16; i++) {
                m = (m + bufB[i]) + bias;
                float thr = m / th - 1.0f;
                ss[i] = (thr >= 0.0f) ? 1.0f : 0.0f;
                if (thr > 0.0f) m -= th;
            }
#pragma unroll
            for (int i = 0; i < 16; i++) op[(size_t)(t0 + 16 + i) * HDIM] = ss[i];
        }
    }
}

// ---------------------------------------------------------------------------
extern "C" void kernel_launch(void* const* d_in, const int* in_sizes, int n_in,
                              void* d_out, int out_size, void* d_ws, size_t ws_size,
                              hipStream_t stream) {
    const float* x    = (const float*)d_in[0];   // (64, 512, 256)
    const float* c1w  = (const float*)d_in[1];   // (512, 256, 3)
    const float* c1b  = (const float*)d_in[2];   // (512,)
    const float* c2w  = (const float*)d_in[3];   // (512, 512, 3)
    const float* c2b  = (const float*)d_in[4];   // (512,)
    const float* th1  = (const float*)d_in[5];   // scalar
    const float* th2  = (const float*)d_in[6];   // scalar
    float* out = (float*)d_out;                  // (64, 512, 512)

    // Workspace layout (floats):
    //   W1T : 131072   (512 KB)   [k=i][n=h]
    //   W2T : 262144   (1 MB)     [k=h][n=j]
    //   bufA: 16777216 (64 MB)    z1, later m2raw   [m][n]
    //   bufS: 16777216 (64 MB)    s1                [m][h]
    float* W1T  = (float*)d_ws;
    float* W2T  = W1T + IDIM * HDIM;
    float* bufA = W2T + HDIM * HDIM;
    float* bufS = bufA + (size_t)MROWS * HDIM;

    // K0: weight extraction
    extract_weights<<<(HDIM * HDIM + 255) / 256, 256, 0, stream>>>(c1w, c2w, W1T, W2T);

    // K1: z1 = x @ W1T + b1   (M=32768, K=256, N=512) -> bufA
    {
        dim3 grid(MROWS / BM, HDIM / BN);
        gemm_f32<<<grid, 256, 0, stream>>>(x, W1T, c1b, bufA, IDIM, 1);
    }

    // K2: s1 scan -> bufS
    lif_scan1<<<MROWS / 64, 64, 0, stream>>>(bufA, bufS, th1);

    // K3: m2raw = s1 @ W2T   (M=32768, K=512, N=512) -> bufA
    {
        dim3 grid(MROWS / BM, HDIM / BN);
        gemm_f32<<<grid, 256, 0, stream>>>(bufS, W2T, (const float*)nullptr, bufA, HDIM, 0);
    }

    // K4: s2 scan -> out
    lif_scan2<<<MROWS / 64, 64, 0, stream>>>(bufA, c2b, th2, out);
}